// Round 2
// baseline (598.571 us; speedup 1.0000x reference)
//
#include <hip/hip_runtime.h>
#include <hip/hip_fp16.h>

typedef _Float16 half8 __attribute__((ext_vector_type(8)));
typedef _Float16 half4 __attribute__((ext_vector_type(4)));
typedef float floatx4 __attribute__((ext_vector_type(4)));

#define DEV __device__ __forceinline__

static constexpr int Bk = 4, Sk = 2048, Uk = 1024, Hk = 16;

DEV void g2l16(const void* g, void* l) {
  __builtin_amdgcn_global_load_lds(
      (const __attribute__((address_space(1))) void*)g,
      (__attribute__((address_space(3))) void*)l, 16, 0, 0);
}

// ---------- detect mask storage: int32 (harness "integer -> const int*") vs raw u8 ----------
// Under int32 {0,1}, bytes at offset i%4!=0 are always 0. Under u8, any true key at such an
// offset sets the flag. Scans 64 KB (rows 0..31 under u8) -- distinguishes all-true & causal.
__global__ void sniff_mask_kernel(const unsigned char* __restrict__ mask, int* __restrict__ flag) {
  __shared__ int s;
  if (threadIdx.x == 0) s = 0;
  __syncthreads();
  int any = 0;
  for (int i = threadIdx.x; i < 65536; i += 256)
    if ((i & 3) && mask[i]) any = 1;
  if (any) atomicOr(&s, 1);
  __syncthreads();
  if (threadIdx.x == 0) *flag = s;  // 1 = u8 layout, 0 = int32 layout
}

// ---------- mask -> u64 bit words (1 bit per key), both layouts ----------
__global__ void mask_bits_kernel(const unsigned char* __restrict__ mask,
                                 const int* __restrict__ flag,
                                 unsigned long long* __restrict__ mb, int nwords) {
  int t = blockIdx.x * blockDim.x + threadIdx.x;
  if (t >= nwords) return;
  unsigned long long bits = 0ULL;
  if (*flag) {  // u8: 1 byte per mask element
    const unsigned long long* p = (const unsigned long long*)mask + (size_t)t * 8;
#pragma unroll
    for (int j = 0; j < 8; ++j) {
      unsigned long long v = p[j];
#pragma unroll
      for (int k = 0; k < 8; ++k)
        bits |= (unsigned long long)(((v >> (8 * k)) & 0xffULL) != 0ULL) << (8 * j + k);
    }
  } else {      // int32: 4 bytes per mask element
    const int4* p = (const int4*)mask + (size_t)t * 16;
#pragma unroll
    for (int j = 0; j < 16; ++j) {
      int4 v = p[j];
      bits |= (unsigned long long)(v.x != 0) << (4 * j + 0);
      bits |= (unsigned long long)(v.y != 0) << (4 * j + 1);
      bits |= (unsigned long long)(v.z != 0) << (4 * j + 2);
      bits |= (unsigned long long)(v.w != 0) << (4 * j + 3);
    }
  }
  mb[t] = bits;
}

// ---------- fp32 -> fp16 ----------
__global__ void convert_x_kernel(const float* __restrict__ X, _Float16* __restrict__ O, int n4) {
  int i = blockIdx.x * blockDim.x + threadIdx.x;
  if (i >= n4) return;
  float4 v = ((const float4*)X)[i];
  half4 o = { (_Float16)v.x, (_Float16)v.y, (_Float16)v.z, (_Float16)v.w };
  ((half4*)O)[i] = o;
}

// ---------- weights: fp32 [K][N] -> fp16 transposed [N][K] ----------
__global__ __launch_bounds__(256) void convert_wt_kernel(
    const float* __restrict__ W0, const float* __restrict__ W1,
    const float* __restrict__ W2, const float* __restrict__ W3,
    _Float16* __restrict__ Out) {
  __shared__ _Float16 t[64][66];  // +2 pad: odd dword stride -> conflict-free transpose read
  int z = blockIdx.z;
  const float* W = (z == 0) ? W0 : (z == 1) ? W1 : (z == 2) ? W2 : W3;
  _Float16* O = Out + (size_t)z * Uk * Uk;
  int kt = blockIdx.x * 64, nt = blockIdx.y * 64;
  int c = threadIdx.x & 63, r4 = threadIdx.x >> 6;
#pragma unroll
  for (int j = 0; j < 16; ++j) {
    int rr = j * 4 + r4;
    t[rr][c] = (_Float16)W[(size_t)(kt + rr) * Uk + nt + c];
  }
  __syncthreads();
#pragma unroll
  for (int j = 0; j < 16; ++j) {
    int rr = j * 4 + r4;  // n-offset
    O[(size_t)(nt + rr) * Uk + kt + c] = t[c][rr];
  }
}

// ---------- V [B,S,H*64] -> Vt [B,H,64,S] ----------
__global__ __launch_bounds__(256) void transpose_v_kernel(
    const _Float16* __restrict__ V, _Float16* __restrict__ Vt) {
  __shared__ _Float16 t[64][66];
  int st = blockIdx.x * 64;
  int bh = blockIdx.y, b = bh >> 4, h = bh & 15;
  int c = threadIdx.x & 63, r4 = threadIdx.x >> 6;
#pragma unroll
  for (int j = 0; j < 16; ++j) {
    int rr = j * 4 + r4;  // s-offset
    t[rr][c] = V[(size_t)(b * Sk + st + rr) * Uk + h * 64 + c];
  }
  __syncthreads();
#pragma unroll
  for (int j = 0; j < 16; ++j) {
    int rr = j * 4 + r4;  // d-index
    Vt[(size_t)((b * Hk + h) * 64 + rr) * Sk + st + c] = t[c][rr];
  }
}

// ---------- GEMM body: C[M,N] = A[M,K] @ Bt[N,K]^T, m97-style 128x128/BK=32 ----------
template <typename OUT_T>
DEV void gemm_body(const _Float16* __restrict__ A, const _Float16* __restrict__ Bt,
                   OUT_T* __restrict__ C, int M, int N, int K, float scale) {
  __shared__ __align__(16) _Float16 As[128 * 32];
  __shared__ __align__(16) _Float16 Bs[128 * 32];
  int tid = threadIdx.x, w = tid >> 6, lane = tid & 63;
  int lr = lane & 15, lg = lane >> 4;
  int wm = w >> 1, wn = w & 1;
  int bm = blockIdx.x * 128, bn = blockIdx.y * 128;

  floatx4 acc[4][4];
#pragma unroll
  for (int m = 0; m < 4; ++m)
#pragma unroll
    for (int n = 0; n < 4; ++n) acc[m][n] = (floatx4){0.f, 0.f, 0.f, 0.f};

  for (int k0 = 0; k0 < K; k0 += 32) {
#pragma unroll
    for (int is = 0; is < 2; ++is) {
      int idx = is * 256 + tid;
      g2l16(&A[(size_t)(bm + (idx >> 2)) * K + k0 + (idx & 3) * 8],
            (char*)As + (is * 256 + w * 64) * 16);
    }
#pragma unroll
    for (int is = 0; is < 2; ++is) {
      int idx = is * 256 + tid;
      g2l16(&Bt[(size_t)(bn + (idx >> 2)) * K + k0 + (idx & 3) * 8],
            (char*)Bs + (is * 256 + w * 64) * 16);
    }
    __syncthreads();  // drains vmcnt(0): staging complete

    half8 af[4], bf[4];
#pragma unroll
    for (int m = 0; m < 4; ++m) af[m] = *(const half8*)&As[(wm * 64 + m * 16 + lr) * 32 + lg * 8];
#pragma unroll
    for (int n = 0; n < 4; ++n) bf[n] = *(const half8*)&Bs[(wn * 64 + n * 16 + lr) * 32 + lg * 8];
#pragma unroll
    for (int m = 0; m < 4; ++m)
#pragma unroll
      for (int n = 0; n < 4; ++n)
        acc[m][n] = __builtin_amdgcn_mfma_f32_16x16x32_f16(af[m], bf[n], acc[m][n], 0, 0, 0);
    __syncthreads();  // all reads done before next stage overwrites
  }

#pragma unroll
  for (int m = 0; m < 4; ++m)
#pragma unroll
    for (int n = 0; n < 4; ++n)
#pragma unroll
      for (int r = 0; r < 4; ++r) {
        int row = bm + wm * 64 + m * 16 + lg * 4 + r;  // C/D: row=(lane>>4)*4+reg
        int col = bn + wn * 64 + n * 16 + lr;          //      col=lane&15
        C[(size_t)row * N + col] = (OUT_T)(acc[m][n][r] * scale);
      }
}

__global__ __launch_bounds__(256) void gemm_qkv_kernel(
    const _Float16* __restrict__ A, const _Float16* __restrict__ WtBase,
    _Float16* __restrict__ OutBase) {
  int z = blockIdx.z;
  const _Float16* Bt = WtBase + (size_t)z * Uk * Uk;
  _Float16* Co = OutBase + (size_t)z * (Bk * Sk) * Uk;
  float scale = (z == 0) ? 0.125f : 1.0f;  // Q pre-scaled by 1/sqrt(64)
  gemm_body<_Float16>(A, Bt, Co, Bk * Sk, Uk, Uk, scale);
}

__global__ __launch_bounds__(256) void gemm_out_kernel(
    const _Float16* __restrict__ A, const _Float16* __restrict__ Bt,
    float* __restrict__ C) {
  gemm_body<float>(A, Bt, C, Bk * Sk, Uk, Uk, 1.0f);
}

// ---------- flash attention: Q-tile 128 (32 rows/wave), KV-tile 64 ----------
__global__ __launch_bounds__(256) void attn_kernel(
    const _Float16* __restrict__ Qg,   // [B*S, U], col h*64+d, pre-scaled
    const _Float16* __restrict__ Kg,   // [B*S, U]
    const _Float16* __restrict__ Vtg,  // [B*H*64, S]
    const unsigned long long* __restrict__ mb,  // [B*S, 32] bit words
    _Float16* __restrict__ Cg) {       // [B*S, U]
  __shared__ __align__(16) _Float16 Ks[64 * 64];      // swizzled [key][d]
  __shared__ __align__(16) _Float16 Vs[64 * 64];      // swizzled [d][key]
  __shared__ __align__(16) _Float16 Ps[4][32 * 64];   // per-wave swizzled [q][key]

  int tid = threadIdx.x, w = tid >> 6, lane = tid & 63;
  int lr = lane & 15, lg = lane >> 4;
  int qb = blockIdx.x * 128, h = blockIdx.y, b = blockIdx.z;
  const float NEGINF = -__builtin_inff();

  // Q fragments hoisted to registers (reused across all 32 KV tiles)
  half8 qf[2][2];
#pragma unroll
  for (int m = 0; m < 2; ++m)
#pragma unroll
    for (int kd = 0; kd < 2; ++kd)
      qf[m][kd] = *(const half8*)&Qg[(size_t)(b * Sk + qb + w * 32 + m * 16 + lr) * Uk +
                                     h * 64 + kd * 32 + lg * 8];

  floatx4 accO[2][4];
  float mrow[2][4], lrow[2][4];
#pragma unroll
  for (int m = 0; m < 2; ++m)
#pragma unroll
    for (int r = 0; r < 4; ++r) { mrow[m][r] = NEGINF; lrow[m][r] = 0.f; }
#pragma unroll
  for (int m = 0; m < 2; ++m)
#pragma unroll
    for (int n = 0; n < 4; ++n) accO[m][n] = (floatx4){0.f, 0.f, 0.f, 0.f};

  for (int kv = 0; kv < Sk; kv += 64) {
    // Stage K tile [64 key][64 d] and Vt tile [64 d][64 key]; LDS dest is linear,
    // source chunk pre-swizzled (chunk ^= row&7) so reads can XOR-deswizzle (G4 fix).
#pragma unroll
    for (int is = 0; is < 2; ++is) {
      int idx = is * 256 + tid;
      int kr = idx >> 3, ch = (idx & 7) ^ (kr & 7);
      g2l16(&Kg[(size_t)(b * Sk + kv + kr) * Uk + h * 64 + ch * 8],
            (char*)Ks + (is * 256 + w * 64) * 16);
    }
#pragma unroll
    for (int is = 0; is < 2; ++is) {
      int idx = is * 256 + tid;
      int dr = idx >> 3, ch = (idx & 7) ^ (dr & 7);
      g2l16(&Vtg[(size_t)((b * Hk + h) * 64 + dr) * Sk + kv + ch * 8],
            (char*)Vs + (is * 256 + w * 64) * 16);
    }
    __syncthreads();

    // scores S = Q K^T  (A=Q frag, B: col=key, k=d contiguous from swizzled Ks)
    floatx4 sc[2][4];
#pragma unroll
    for (int m = 0; m < 2; ++m)
#pragma unroll
      for (int n = 0; n < 4; ++n) sc[m][n] = (floatx4){0.f, 0.f, 0.f, 0.f};
#pragma unroll
    for (int kd = 0; kd < 2; ++kd) {
      half8 bk[4];
#pragma unroll
      for (int n = 0; n < 4; ++n) {
        int key = n * 16 + lr;
        bk[n] = *(const half8*)&Ks[key * 64 + ((kd * 4 + lg) ^ (key & 7)) * 8];
      }
#pragma unroll
      for (int m = 0; m < 2; ++m)
#pragma unroll
        for (int n = 0; n < 4; ++n)
          sc[m][n] = __builtin_amdgcn_mfma_f32_16x16x32_f16(qf[m][kd], bk[n], sc[m][n], 0, 0, 0);
    }

    // mask + online softmax (row = q: 16 lanes share a row-group; reduce over lr)
    const unsigned long long* mbp = mb + ((size_t)b * Sk + qb + w * 32) * 32 + (kv >> 6);
#pragma unroll
    for (int m = 0; m < 2; ++m) {
#pragma unroll
      for (int r = 0; r < 4; ++r) {
        unsigned long long wmask = mbp[(size_t)(m * 16 + lg * 4 + r) * 32];
        float mx = NEGINF;
#pragma unroll
        for (int n = 0; n < 4; ++n) {
          float s = sc[m][n][r];
          s = ((wmask >> (n * 16 + lr)) & 1ULL) ? s : NEGINF;
          sc[m][n][r] = s;
          mx = fmaxf(mx, s);
        }
        mx = fmaxf(mx, __shfl_xor(mx, 1));
        mx = fmaxf(mx, __shfl_xor(mx, 2));
        mx = fmaxf(mx, __shfl_xor(mx, 4));
        mx = fmaxf(mx, __shfl_xor(mx, 8));
        float mn = fmaxf(mrow[m][r], mx);
        float alpha = (mn == mrow[m][r]) ? 1.0f : __expf(mrow[m][r] - mn);
        mrow[m][r] = mn;
        float rs = 0.f;
        bool dead = (mn == NEGINF);  // row fully masked so far
#pragma unroll
        for (int n = 0; n < 4; ++n) {
          float s = sc[m][n][r];
          float p = dead ? 0.0f : __expf(s - mn);  // exp(-inf)=0 handles masked lanes
          sc[m][n][r] = p;
          rs += p;
        }
        rs += __shfl_xor(rs, 1);
        rs += __shfl_xor(rs, 2);
        rs += __shfl_xor(rs, 4);
        rs += __shfl_xor(rs, 8);
        lrow[m][r] = lrow[m][r] * alpha + rs;
#pragma unroll
        for (int nd = 0; nd < 4; ++nd) accO[m][nd][r] *= alpha;
        // write P (fp16) to per-wave swizzled LDS for the PV A-operand
        int q = m * 16 + lg * 4 + r;
#pragma unroll
        for (int n = 0; n < 4; ++n) {
          int key = n * 16 + lr;
          Ps[w][q * 64 + (((key >> 3) ^ (q & 7)) * 8) + (key & 7)] = (_Float16)sc[m][n][r];
        }
      }
    }

    // PV: A = P[q][key], B: col=d, k=key contiguous from swizzled Vs
#pragma unroll
    for (int kd = 0; kd < 2; ++kd) {
      half8 pf[2], vf[4];
#pragma unroll
      for (int m = 0; m < 2; ++m) {
        int q = m * 16 + lr;
        pf[m] = *(const half8*)&Ps[w][q * 64 + (((kd * 4 + lg) ^ (q & 7)) * 8)];
      }
#pragma unroll
      for (int nd = 0; nd < 4; ++nd) {
        int d = nd * 16 + lr;
        vf[nd] = *(const half8*)&Vs[d * 64 + (((kd * 4 + lg) ^ (d & 7)) * 8)];
      }
#pragma unroll
      for (int m = 0; m < 2; ++m)
#pragma unroll
        for (int nd = 0; nd < 4; ++nd)
          accO[m][nd] = __builtin_amdgcn_mfma_f32_16x16x32_f16(pf[m], vf[nd], accO[m][nd], 0, 0, 0);
    }
    __syncthreads();  // all waves done with Ks/Vs before next stage
  }

  // epilogue: divide by l (0 if row fully masked), write C[b,q,h*64+d] fp16
#pragma unroll
  for (int m = 0; m < 2; ++m)
#pragma unroll
    for (int r = 0; r < 4; ++r) {
      float l = lrow[m][r];
      float inv = (l > 0.f) ? 1.0f / l : 0.0f;
      int q = qb + w * 32 + m * 16 + lg * 4 + r;
#pragma unroll
      for (int nd = 0; nd < 4; ++nd)
        Cg[(size_t)(b * Sk + q) * Uk + h * 64 + nd * 16 + lr] =
            (_Float16)(accO[m][nd][r] * inv);
    }
}

// ---------- launch ----------
extern "C" void kernel_launch(void* const* d_in, const int* in_sizes, int n_in,
                              void* d_out, int out_size, void* d_ws, size_t ws_size,
                              hipStream_t stream) {
  const float* x = (const float*)d_in[0];
  const unsigned char* mask = (const unsigned char*)d_in[1];
  const float* wq = (const float*)d_in[2];
  const float* wk = (const float*)d_in[3];
  const float* wv = (const float*)d_in[4];
  const float* wo = (const float*)d_in[5];
  float* out = (float*)d_out;

  char* ws = (char*)d_ws;
  _Float16* wt  = (_Float16*)(ws);                       // 4 x 1024x1024 fp16 = 8 MB
  _Float16* x16 = (_Float16*)(ws + (8ull << 20));        // 16 MB
  _Float16* c16 = x16;                                   // alias: x16 dead after QKV GEMMs
  _Float16* qkv = (_Float16*)(ws + (24ull << 20));       // Q,K,V: 48 MB
  _Float16* vt  = (_Float16*)(ws + (72ull << 20));       // 16 MB
  unsigned long long* mbw = (unsigned long long*)(ws + (88ull << 20));  // 2 MB
  int* mflag = (int*)(ws + (90ull << 20));               // 4 B

  const size_t MU = (size_t)Bk * Sk * Uk;  // 8.4M elements

  sniff_mask_kernel<<<dim3(1), dim3(256), 0, stream>>>(mask, mflag);
  mask_bits_kernel<<<dim3(1024), dim3(256), 0, stream>>>(mask, mflag, mbw, Bk * Sk * (Sk / 64));
  convert_x_kernel<<<dim3(8192), dim3(256), 0, stream>>>(x, x16, (int)(MU / 4));
  convert_wt_kernel<<<dim3(16, 16, 4), dim3(256), 0, stream>>>(wq, wk, wv, wo, wt);
  gemm_qkv_kernel<<<dim3(64, 8, 3), dim3(256), 0, stream>>>(x16, wt, qkv);
  transpose_v_kernel<<<dim3(32, 64), dim3(256), 0, stream>>>(qkv + 2 * MU, vt);
  attn_kernel<<<dim3(16, 16, 4), dim3(256), 0, stream>>>(qkv, qkv + MU, vt, mbw, c16);
  gemm_out_kernel<<<dim3(64, 8), dim3(256), 0, stream>>>(c16, wt + 3ull * Uk * Uk, out);
}

// Round 4
// 509.586 us; speedup vs baseline: 1.1746x; 1.1746x over previous
//
#include <hip/hip_runtime.h>
#include <hip/hip_fp16.h>

typedef _Float16 half8 __attribute__((ext_vector_type(8)));
typedef _Float16 half4 __attribute__((ext_vector_type(4)));
typedef __fp16 fp16x2 __attribute__((ext_vector_type(2)));
typedef float floatx4 __attribute__((ext_vector_type(4)));
typedef float f32x16 __attribute__((ext_vector_type(16)));

#define DEV __device__ __forceinline__

static constexpr int Bk = 4, Sk = 2048, Uk = 1024, Hk = 16;

DEV void g2l16(const void* g, void* l) {
  __builtin_amdgcn_global_load_lds(
      (const __attribute__((address_space(1))) void*)g,
      (__attribute__((address_space(3))) void*)l, 16, 0, 0);
}

DEV unsigned int pkrtz(float a, float b) {
  union { fp16x2 h; unsigned int u; } t;
  t.h = __builtin_amdgcn_cvt_pkrtz(a, b);
  return t.u;
}

// ---------- detect mask storage: int32 vs raw u8 ----------
__global__ void sniff_mask_kernel(const unsigned char* __restrict__ mask, int* __restrict__ flag) {
  __shared__ int s;
  if (threadIdx.x == 0) s = 0;
  __syncthreads();
  int any = 0;
  for (int i = threadIdx.x; i < 65536; i += 256)
    if ((i & 3) && mask[i]) any = 1;
  if (any) atomicOr(&s, 1);
  __syncthreads();
  if (threadIdx.x == 0) *flag = s;  // 1 = u8 layout, 0 = int32 layout
}

// ---------- mask -> u64 bit words (1 bit per key), both layouts ----------
__global__ void mask_bits_kernel(const unsigned char* __restrict__ mask,
                                 const int* __restrict__ flag,
                                 unsigned long long* __restrict__ mb, int nwords) {
  int t = blockIdx.x * blockDim.x + threadIdx.x;
  if (t >= nwords) return;
  unsigned long long bits = 0ULL;
  if (*flag) {
    const unsigned long long* p = (const unsigned long long*)mask + (size_t)t * 8;
#pragma unroll
    for (int j = 0; j < 8; ++j) {
      unsigned long long v = p[j];
#pragma unroll
      for (int k = 0; k < 8; ++k)
        bits |= (unsigned long long)(((v >> (8 * k)) & 0xffULL) != 0ULL) << (8 * j + k);
    }
  } else {
    const int4* p = (const int4*)mask + (size_t)t * 16;
#pragma unroll
    for (int j = 0; j < 16; ++j) {
      int4 v = p[j];
      bits |= (unsigned long long)(v.x != 0) << (4 * j + 0);
      bits |= (unsigned long long)(v.y != 0) << (4 * j + 1);
      bits |= (unsigned long long)(v.z != 0) << (4 * j + 2);
      bits |= (unsigned long long)(v.w != 0) << (4 * j + 3);
    }
  }
  mb[t] = bits;
}

// ---------- fp32 -> fp16 ----------
__global__ void convert_x_kernel(const float* __restrict__ X, _Float16* __restrict__ O, int n4) {
  int i = blockIdx.x * blockDim.x + threadIdx.x;
  if (i >= n4) return;
  float4 v = ((const float4*)X)[i];
  half4 o = { (_Float16)v.x, (_Float16)v.y, (_Float16)v.z, (_Float16)v.w };
  ((half4*)O)[i] = o;
}

// ---------- weights: fp32 [K][N] -> fp16 transposed [N][K] ----------
__global__ __launch_bounds__(256) void convert_wt_kernel(
    const float* __restrict__ W0, const float* __restrict__ W1,
    const float* __restrict__ W2, const float* __restrict__ W3,
    _Float16* __restrict__ Out) {
  __shared__ _Float16 t[64][66];
  int z = blockIdx.z;
  const float* W = (z == 0) ? W0 : (z == 1) ? W1 : (z == 2) ? W2 : W3;
  _Float16* O = Out + (size_t)z * Uk * Uk;
  int kt = blockIdx.x * 64, nt = blockIdx.y * 64;
  int c = threadIdx.x & 63, r4 = threadIdx.x >> 6;
#pragma unroll
  for (int j = 0; j < 16; ++j) {
    int rr = j * 4 + r4;
    t[rr][c] = (_Float16)W[(size_t)(kt + rr) * Uk + nt + c];
  }
  __syncthreads();
#pragma unroll
  for (int j = 0; j < 16; ++j) {
    int rr = j * 4 + r4;
    O[(size_t)(nt + rr) * Uk + kt + c] = t[c][rr];
  }
}

// ---------- V [B,S,H*64] -> Vt [B,H,64,S] ----------
__global__ __launch_bounds__(256) void transpose_v_kernel(
    const _Float16* __restrict__ V, _Float16* __restrict__ Vt) {
  __shared__ _Float16 t[64][66];
  int st = blockIdx.x * 64;
  int bh = blockIdx.y, b = bh >> 4, h = bh & 15;
  int c = threadIdx.x & 63, r4 = threadIdx.x >> 6;
#pragma unroll
  for (int j = 0; j < 16; ++j) {
    int rr = j * 4 + r4;
    t[rr][c] = V[(size_t)(b * Sk + st + rr) * Uk + h * 64 + c];
  }
  __syncthreads();
#pragma unroll
  for (int j = 0; j < 16; ++j) {
    int rr = j * 4 + r4;
    Vt[(size_t)((b * Hk + h) * 64 + rr) * Sk + st + c] = t[c][rr];
  }
}

// ---------- GEMM body: C[M,N] = A[M,K] @ Bt[N,K]^T, m97-style 128x128/BK=32 ----------
template <typename OUT_T>
DEV void gemm_body(const _Float16* __restrict__ A, const _Float16* __restrict__ Bt,
                   OUT_T* __restrict__ C, int M, int N, int K, float scale) {
  __shared__ __align__(16) _Float16 As[128 * 32];
  __shared__ __align__(16) _Float16 Bs[128 * 32];
  int tid = threadIdx.x, w = tid >> 6, lane = tid & 63;
  int lr = lane & 15, lg = lane >> 4;
  int wm = w >> 1, wn = w & 1;
  int bm = blockIdx.x * 128, bn = blockIdx.y * 128;

  floatx4 acc[4][4];
#pragma unroll
  for (int m = 0; m < 4; ++m)
#pragma unroll
    for (int n = 0; n < 4; ++n) acc[m][n] = (floatx4){0.f, 0.f, 0.f, 0.f};

  for (int k0 = 0; k0 < K; k0 += 32) {
#pragma unroll
    for (int is = 0; is < 2; ++is) {
      int idx = is * 256 + tid;
      g2l16(&A[(size_t)(bm + (idx >> 2)) * K + k0 + (idx & 3) * 8],
            (char*)As + (is * 256 + w * 64) * 16);
    }
#pragma unroll
    for (int is = 0; is < 2; ++is) {
      int idx = is * 256 + tid;
      g2l16(&Bt[(size_t)(bn + (idx >> 2)) * K + k0 + (idx & 3) * 8],
            (char*)Bs + (is * 256 + w * 64) * 16);
    }
    __syncthreads();

    half8 af[4], bf[4];
#pragma unroll
    for (int m = 0; m < 4; ++m) af[m] = *(const half8*)&As[(wm * 64 + m * 16 + lr) * 32 + lg * 8];
#pragma unroll
    for (int n = 0; n < 4; ++n) bf[n] = *(const half8*)&Bs[(wn * 64 + n * 16 + lr) * 32 + lg * 8];
#pragma unroll
    for (int m = 0; m < 4; ++m)
#pragma unroll
      for (int n = 0; n < 4; ++n)
        acc[m][n] = __builtin_amdgcn_mfma_f32_16x16x32_f16(af[m], bf[n], acc[m][n], 0, 0, 0);
    __syncthreads();
  }

#pragma unroll
  for (int m = 0; m < 4; ++m)
#pragma unroll
    for (int n = 0; n < 4; ++n)
#pragma unroll
      for (int r = 0; r < 4; ++r) {
        int row = bm + wm * 64 + m * 16 + lg * 4 + r;
        int col = bn + wn * 64 + n * 16 + lr;
        C[(size_t)row * N + col] = (OUT_T)(acc[m][n][r] * scale);
      }
}

__global__ __launch_bounds__(256) void gemm_qkv_kernel(
    const _Float16* __restrict__ A, const _Float16* __restrict__ WtBase,
    _Float16* __restrict__ OutBase) {
  int z = blockIdx.z;
  const _Float16* Bt = WtBase + (size_t)z * Uk * Uk;
  _Float16* Co = OutBase + (size_t)z * (Bk * Sk) * Uk;
  float scale = (z == 0) ? 0.125f : 1.0f;
  gemm_body<_Float16>(A, Bt, Co, Bk * Sk, Uk, Uk, scale);
}

__global__ __launch_bounds__(256) void gemm_out_kernel(
    const _Float16* __restrict__ A, const _Float16* __restrict__ Bt,
    float* __restrict__ C) {
  gemm_body<float>(A, Bt, C, Bk * Sk, Uk, Uk, 1.0f);
}

// ---------- flash attention, 8-wave 32x32 swapped-QK^T in-register softmax ----------
// grid (H, B, S/256); block 512. Per wave: 32 q-rows; KV-tile 64 keys, 32 iters.
// sc = mfma(K,Q): lane <-> q (col=lane&31), keys in regs: off=(r&3)+8*(r>>2)+4*hi+32n
// PV = mfma(P,V): lane <-> d, q in regs -> coalesced stores; alpha via deferred rescale.
__global__ __launch_bounds__(512, 4) void attn_kernel(
    const _Float16* __restrict__ Qg,   // [B*S, U], pre-scaled by 1/8
    const _Float16* __restrict__ Kg,   // [B*S, U]
    const _Float16* __restrict__ Vtg,  // [B*H*64, S]
    const unsigned long long* __restrict__ mb,  // [B*S, 32] bit words
    _Float16* __restrict__ Cg) {       // [B*S, U]
  __shared__ __align__(16) _Float16 Ks[2][64 * 64];  // [key][d], chunk-swizzled
  __shared__ __align__(16) _Float16 Vs[2][64 * 64];  // [d][key], chunk-swizzled

  const int tid = threadIdx.x, w = tid >> 6;
  const int l31 = tid & 31, hi = (tid & 63) >> 5;
  const int h = blockIdx.x, b = blockIdx.y, qb = blockIdx.z * 256;
  const float NEGINF = -__builtin_inff();

  // staging source (per thread): row kr, pre-swizzled chunk ch (G4 both-sides rule)
  const int kr = tid >> 3;
  const int ch = (tid & 7) ^ (kr & 7);
  const _Float16* kSrc = Kg + (size_t)(b * Sk + kr) * Uk + h * 64 + ch * 8;
  const _Float16* vSrc = Vtg + (size_t)((b * Hk + h) * 64 + kr) * Sk + ch * 8;

  // stage tile 0 into buffer 0
  g2l16(kSrc, (char*)Ks[0] + w * 1024);
  g2l16(vSrc, (char*)Vs[0] + w * 1024);

  // Q fragments: B-operand, col=q(lane&31), k=d (hi*8+e within 16-chunk)
  const int qrow = qb + w * 32 + l31;
  const size_t qoff = (size_t)(b * Sk + qrow) * Uk + h * 64 + hi * 8;
  half8 qf[4];
#pragma unroll
  for (int kc = 0; kc < 4; ++kc) qf[kc] = *(const half8*)&Qg[qoff + kc * 16];

  const unsigned long long* mrow = mb + (size_t)(b * Sk + qrow) * 32;

  f32x16 accO[2];
#pragma unroll
  for (int dt = 0; dt < 2; ++dt)
#pragma unroll
    for (int r = 0; r < 16; ++r) accO[dt][r] = 0.f;
  float m = NEGINF, l = 0.f;

  int cur = 0;
  __syncthreads();  // tile 0 staged

  for (int it = 0; it < 32; ++it) {
    if (it + 1 < 32) {  // issue next-tile loads; they fly during this tile's compute
      g2l16(kSrc + (size_t)(it + 1) * 64 * Uk, (char*)Ks[cur ^ 1] + w * 1024);
      g2l16(vSrc + (it + 1) * 64, (char*)Vs[cur ^ 1] + w * 1024);
    }
    const unsigned long long wm = mrow[it];

    // ---- QK^T ----
    f32x16 sc[2];
#pragma unroll
    for (int n = 0; n < 2; ++n)
#pragma unroll
      for (int r = 0; r < 16; ++r) sc[n][r] = 0.f;
#pragma unroll
    for (int n = 0; n < 2; ++n)
#pragma unroll
      for (int kc = 0; kc < 4; ++kc) {
        half8 kf = *(const half8*)&Ks[cur][(n * 32 + l31) * 64 + ((kc * 2 + hi) ^ (l31 & 7)) * 8];
        sc[n] = __builtin_amdgcn_mfma_f32_32x32x16_f16(kf, qf[kc], sc[n], 0, 0, 0);
      }

    // ---- mask + online softmax (lane owns one q-row; keys in regs) ----
    const bool tmask = !__all(wm == ~0ULL);
    if (tmask) {
#pragma unroll
      for (int n = 0; n < 2; ++n)
#pragma unroll
        for (int r = 0; r < 16; ++r) {
          int off = n * 32 + (r & 3) + 8 * (r >> 2) + (hi << 2);
          sc[n][r] = ((wm >> off) & 1ULL) ? sc[n][r] : NEGINF;
        }
    }
    float mx = NEGINF;
#pragma unroll
    for (int n = 0; n < 2; ++n)
#pragma unroll
      for (int r = 0; r < 16; ++r) mx = fmaxf(mx, sc[n][r]);
    mx = fmaxf(mx, __shfl_xor(mx, 32));

    const bool skip = __all(mx <= m + 8.f);  // deferred rescale (T13)
    float alpha = 1.f;
    if (!skip) {
      float mn = fmaxf(m, mx);
      alpha = (mn > NEGINF) ? __expf(m - mn) : 0.f;
      m = mn;
    }
    float rs = 0.f;
    if (tmask) {
#pragma unroll
      for (int n = 0; n < 2; ++n)
#pragma unroll
        for (int r = 0; r < 16; ++r) {
          float e = __expf(fmaxf(sc[n][r] - m, -80.f));  // guard dead rows (NaN-free)
          sc[n][r] = e; rs += e;
        }
    } else {
#pragma unroll
      for (int n = 0; n < 2; ++n)
#pragma unroll
        for (int r = 0; r < 16; ++r) {
          float e = __expf(sc[n][r] - m);
          sc[n][r] = e; rs += e;
        }
    }
    rs += __shfl_xor(rs, 32);
    l = l * alpha + rs;
    if (!skip) {  // wave-uniform, rare: broadcast alpha per accO q-reg
#pragma unroll
      for (int r = 0; r < 16; ++r) {
        float ar = __shfl(alpha, (r & 3) + 8 * (r >> 2) + (hi << 2));
        accO[0][r] *= ar;
        accO[1][r] *= ar;
      }
    }

    // ---- pack P (fp16) and build PV A-frags via half-exchange (T12 pattern) ----
    unsigned int pw0[2][4], pw1[2][4];
#pragma unroll
    for (int n = 0; n < 2; ++n)
#pragma unroll
      for (int g = 0; g < 4; ++g) {
        pw0[n][g] = pkrtz(sc[n][4 * g + 0], sc[n][4 * g + 1]);
        pw1[n][g] = pkrtz(sc[n][4 * g + 2], sc[n][4 * g + 3]);
      }
#pragma unroll
    for (int kt = 0; kt < 4; ++kt) {
      const int n = kt >> 1, t = kt & 1;
      // partner needs our group (2t + !hi); we receive its (2t + hi)
      unsigned int s0 = __shfl_xor((int)(hi ? pw0[n][2 * t] : pw0[n][2 * t + 1]), 32);
      unsigned int s1 = __shfl_xor((int)(hi ? pw1[n][2 * t] : pw1[n][2 * t + 1]), 32);
      unsigned int o0 = hi ? pw0[n][2 * t + 1] : pw0[n][2 * t];
      unsigned int o1 = hi ? pw1[n][2 * t + 1] : pw1[n][2 * t];
      union { half8 hh; unsigned int u[4]; } pa;
      pa.u[0] = hi ? s0 : o0;
      pa.u[1] = hi ? s1 : o1;
      pa.u[2] = hi ? o0 : s0;
      pa.u[3] = hi ? o1 : s1;
#pragma unroll
      for (int dt = 0; dt < 2; ++dt) {
        half8 vf = *(const half8*)&Vs[cur][(dt * 32 + l31) * 64 + ((kt * 2 + hi) ^ (l31 & 7)) * 8];
        accO[dt] = __builtin_amdgcn_mfma_f32_32x32x16_f16(pa.hh, vf, accO[dt], 0, 0, 0);
      }
    }
    __syncthreads();  // next tile staged (vmcnt drained) & all reads of cur done
    cur ^= 1;
  }

  // ---- epilogue: /l (per-q via shfl), coalesced fp16 stores ----
  float inv = (l > 1e-30f) ? 1.0f / l : 0.0f;
#pragma unroll
  for (int r = 0; r < 16; ++r) {
    const int qd = (r & 3) + 8 * (r >> 2) + 4 * hi;  // q owned by this reg
    float invr = __shfl(inv, qd);
#pragma unroll
    for (int dt = 0; dt < 2; ++dt)
      Cg[(size_t)(b * Sk + qb + w * 32 + qd) * Uk + h * 64 + dt * 32 + l31] =
          (_Float16)(accO[dt][r] * invr);
  }
}

// ---------- launch ----------
extern "C" void kernel_launch(void* const* d_in, const int* in_sizes, int n_in,
                              void* d_out, int out_size, void* d_ws, size_t ws_size,
                              hipStream_t stream) {
  const float* x = (const float*)d_in[0];
  const unsigned char* mask = (const unsigned char*)d_in[1];
  const float* wq = (const float*)d_in[2];
  const float* wk = (const float*)d_in[3];
  const float* wv = (const float*)d_in[4];
  const float* wo = (const float*)d_in[5];
  float* out = (float*)d_out;

  char* ws = (char*)d_ws;
  _Float16* wt  = (_Float16*)(ws);                       // 8 MB
  _Float16* x16 = (_Float16*)(ws + (8ull << 20));        // 16 MB
  _Float16* c16 = x16;                                   // alias: x16 dead after QKV GEMMs
  _Float16* qkv = (_Float16*)(ws + (24ull << 20));       // 48 MB
  _Float16* vt  = (_Float16*)(ws + (72ull << 20));       // 16 MB
  unsigned long long* mbw = (unsigned long long*)(ws + (88ull << 20));  // 2 MB
  int* mflag = (int*)(ws + (90ull << 20));

  const size_t MU = (size_t)Bk * Sk * Uk;

  sniff_mask_kernel<<<dim3(1), dim3(256), 0, stream>>>(mask, mflag);
  mask_bits_kernel<<<dim3(1024), dim3(256), 0, stream>>>(mask, mflag, mbw, Bk * Sk * (Sk / 64));
  convert_x_kernel<<<dim3(8192), dim3(256), 0, stream>>>(x, x16, (int)(MU / 4));
  convert_wt_kernel<<<dim3(16, 16, 4), dim3(256), 0, stream>>>(wq, wk, wv, wo, wt);
  gemm_qkv_kernel<<<dim3(64, 8, 3), dim3(256), 0, stream>>>(x16, wt, qkv);
  transpose_v_kernel<<<dim3(32, 64), dim3(256), 0, stream>>>(qkv + 2 * MU, vt);
  attn_kernel<<<dim3(Hk, Bk, Sk / 256), dim3(512), 0, stream>>>(qkv, qkv + MU, vt, mbw, c16);
  gemm_out_kernel<<<dim3(64, 8), dim3(256), 0, stream>>>(c16, wt + 3ull * Uk * Uk, out);
}

// Round 5
// 500.002 us; speedup vs baseline: 1.1971x; 1.0192x over previous
//
#include <hip/hip_runtime.h>
#include <hip/hip_fp16.h>

typedef _Float16 half8 __attribute__((ext_vector_type(8)));
typedef _Float16 half4 __attribute__((ext_vector_type(4)));
typedef __fp16 fp16x2 __attribute__((ext_vector_type(2)));
typedef float floatx4 __attribute__((ext_vector_type(4)));
typedef float f32x16 __attribute__((ext_vector_type(16)));

#define DEV __device__ __forceinline__

static constexpr int Bk = 4, Sk = 2048, Uk = 1024, Hk = 16;

DEV void g2l16(const void* g, void* l) {
  __builtin_amdgcn_global_load_lds(
      (const __attribute__((address_space(1))) void*)g,
      (__attribute__((address_space(3))) void*)l, 16, 0, 0);
}

DEV unsigned int pkrtz(float a, float b) {
  union { fp16x2 h; unsigned int u; } t;
  t.h = __builtin_amdgcn_cvt_pkrtz(a, b);
  return t.u;
}

// ---------- detect mask storage: int32 vs raw u8 ----------
__global__ void sniff_mask_kernel(const unsigned char* __restrict__ mask, int* __restrict__ flag) {
  __shared__ int s;
  if (threadIdx.x == 0) s = 0;
  __syncthreads();
  int any = 0;
  for (int i = threadIdx.x; i < 65536; i += 256)
    if ((i & 3) && mask[i]) any = 1;
  if (any) atomicOr(&s, 1);
  __syncthreads();
  if (threadIdx.x == 0) *flag = s;  // 1 = u8 layout, 0 = int32 layout
}

// ---------- mask -> u64 bit words (1 bit per key), both layouts ----------
__global__ void mask_bits_kernel(const unsigned char* __restrict__ mask,
                                 const int* __restrict__ flag,
                                 unsigned long long* __restrict__ mb, int nwords) {
  int t = blockIdx.x * blockDim.x + threadIdx.x;
  if (t >= nwords) return;
  unsigned long long bits = 0ULL;
  if (*flag) {
    const unsigned long long* p = (const unsigned long long*)mask + (size_t)t * 8;
#pragma unroll
    for (int j = 0; j < 8; ++j) {
      unsigned long long v = p[j];
#pragma unroll
      for (int k = 0; k < 8; ++k)
        bits |= (unsigned long long)(((v >> (8 * k)) & 0xffULL) != 0ULL) << (8 * j + k);
    }
  } else {
    const int4* p = (const int4*)mask + (size_t)t * 16;
#pragma unroll
    for (int j = 0; j < 16; ++j) {
      int4 v = p[j];
      bits |= (unsigned long long)(v.x != 0) << (4 * j + 0);
      bits |= (unsigned long long)(v.y != 0) << (4 * j + 1);
      bits |= (unsigned long long)(v.z != 0) << (4 * j + 2);
      bits |= (unsigned long long)(v.w != 0) << (4 * j + 3);
    }
  }
  mb[t] = bits;
}

// ---------- fp32 -> fp16 ----------
__global__ void convert_x_kernel(const float* __restrict__ X, _Float16* __restrict__ O, int n4) {
  int i = blockIdx.x * blockDim.x + threadIdx.x;
  if (i >= n4) return;
  float4 v = ((const float4*)X)[i];
  half4 o = { (_Float16)v.x, (_Float16)v.y, (_Float16)v.z, (_Float16)v.w };
  ((half4*)O)[i] = o;
}

// ---------- weights: fp32 [K][N] -> fp16 transposed [N][K] ----------
__global__ __launch_bounds__(256) void convert_wt_kernel(
    const float* __restrict__ W0, const float* __restrict__ W1,
    const float* __restrict__ W2, const float* __restrict__ W3,
    _Float16* __restrict__ Out) {
  __shared__ _Float16 t[64][66];
  int z = blockIdx.z;
  const float* W = (z == 0) ? W0 : (z == 1) ? W1 : (z == 2) ? W2 : W3;
  _Float16* O = Out + (size_t)z * Uk * Uk;
  int kt = blockIdx.x * 64, nt = blockIdx.y * 64;
  int c = threadIdx.x & 63, r4 = threadIdx.x >> 6;
#pragma unroll
  for (int j = 0; j < 16; ++j) {
    int rr = j * 4 + r4;
    t[rr][c] = (_Float16)W[(size_t)(kt + rr) * Uk + nt + c];
  }
  __syncthreads();
#pragma unroll
  for (int j = 0; j < 16; ++j) {
    int rr = j * 4 + r4;
    O[(size_t)(nt + rr) * Uk + kt + c] = t[c][rr];
  }
}

// ---------- V [B,S,H*64] -> Vt [B,H,64,S] ----------
__global__ __launch_bounds__(256) void transpose_v_kernel(
    const _Float16* __restrict__ V, _Float16* __restrict__ Vt) {
  __shared__ _Float16 t[64][66];
  int st = blockIdx.x * 64;
  int bh = blockIdx.y, b = bh >> 4, h = bh & 15;
  int c = threadIdx.x & 63, r4 = threadIdx.x >> 6;
#pragma unroll
  for (int j = 0; j < 16; ++j) {
    int rr = j * 4 + r4;
    t[rr][c] = V[(size_t)(b * Sk + st + rr) * Uk + h * 64 + c];
  }
  __syncthreads();
#pragma unroll
  for (int j = 0; j < 16; ++j) {
    int rr = j * 4 + r4;
    Vt[(size_t)((b * Hk + h) * 64 + rr) * Sk + st + c] = t[c][rr];
  }
}

// ---------- GEMM body: C[M,N] = A[M,K] @ Bt[N,K]^T, m97-style 128x128/BK=32 ----------
template <typename OUT_T>
DEV void gemm_body(const _Float16* __restrict__ A, const _Float16* __restrict__ Bt,
                   OUT_T* __restrict__ C, int M, int N, int K, float scale) {
  __shared__ __align__(16) _Float16 As[128 * 32];
  __shared__ __align__(16) _Float16 Bs[128 * 32];
  int tid = threadIdx.x, w = tid >> 6, lane = tid & 63;
  int lr = lane & 15, lg = lane >> 4;
  int wm = w >> 1, wn = w & 1;
  int bm = blockIdx.x * 128, bn = blockIdx.y * 128;

  floatx4 acc[4][4];
#pragma unroll
  for (int m = 0; m < 4; ++m)
#pragma unroll
    for (int n = 0; n < 4; ++n) acc[m][n] = (floatx4){0.f, 0.f, 0.f, 0.f};

  for (int k0 = 0; k0 < K; k0 += 32) {
#pragma unroll
    for (int is = 0; is < 2; ++is) {
      int idx = is * 256 + tid;
      g2l16(&A[(size_t)(bm + (idx >> 2)) * K + k0 + (idx & 3) * 8],
            (char*)As + (is * 256 + w * 64) * 16);
    }
#pragma unroll
    for (int is = 0; is < 2; ++is) {
      int idx = is * 256 + tid;
      g2l16(&Bt[(size_t)(bn + (idx >> 2)) * K + k0 + (idx & 3) * 8],
            (char*)Bs + (is * 256 + w * 64) * 16);
    }
    __syncthreads();

    half8 af[4], bf[4];
#pragma unroll
    for (int m = 0; m < 4; ++m) af[m] = *(const half8*)&As[(wm * 64 + m * 16 + lr) * 32 + lg * 8];
#pragma unroll
    for (int n = 0; n < 4; ++n) bf[n] = *(const half8*)&Bs[(wn * 64 + n * 16 + lr) * 32 + lg * 8];
#pragma unroll
    for (int m = 0; m < 4; ++m)
#pragma unroll
      for (int n = 0; n < 4; ++n)
        acc[m][n] = __builtin_amdgcn_mfma_f32_16x16x32_f16(af[m], bf[n], acc[m][n], 0, 0, 0);
    __syncthreads();
  }

#pragma unroll
  for (int m = 0; m < 4; ++m)
#pragma unroll
    for (int n = 0; n < 4; ++n)
#pragma unroll
      for (int r = 0; r < 4; ++r) {
        int row = bm + wm * 64 + m * 16 + lg * 4 + r;
        int col = bn + wn * 64 + n * 16 + lr;
        C[(size_t)row * N + col] = (OUT_T)(acc[m][n][r] * scale);
      }
}

__global__ __launch_bounds__(256) void gemm_qkv_kernel(
    const _Float16* __restrict__ A, const _Float16* __restrict__ WtBase,
    _Float16* __restrict__ OutBase) {
  int z = blockIdx.z;
  const _Float16* Bt = WtBase + (size_t)z * Uk * Uk;
  _Float16* Co = OutBase + (size_t)z * (Bk * Sk) * Uk;
  float scale = (z == 0) ? 0.125f : 1.0f;
  gemm_body<_Float16>(A, Bt, Co, Bk * Sk, Uk, Uk, scale);
}

__global__ __launch_bounds__(256) void gemm_out_kernel(
    const _Float16* __restrict__ A, const _Float16* __restrict__ Bt,
    float* __restrict__ C) {
  gemm_body<float>(A, Bt, C, Bk * Sk, Uk, Uk, 1.0f);
}

// ---------- flash attention, 8-wave 32x32 swapped-QK^T in-register softmax ----------
// Register budget note: launch_bounds(512,4) => 128 unified regs/wave. Peak live set:
// accO(32,AGPR) + qf(16) + sc(32, dies into pkL/pkH(16) during exp+pack fusion) + addr/temps
// ~= 110 -> no spill (round-4 kept sc AND pw live together -> spilled, WRITE_SIZE 130MB).
__global__ __launch_bounds__(512, 4) void attn_kernel(
    const _Float16* __restrict__ Qg,   // [B*S, U], pre-scaled by 1/8
    const _Float16* __restrict__ Kg,   // [B*S, U]
    const _Float16* __restrict__ Vtg,  // [B*H*64, S]
    const unsigned long long* __restrict__ mb,  // [B*S, 32] bit words
    _Float16* __restrict__ Cg) {       // [B*S, U]
  __shared__ __align__(16) _Float16 Ks[2][64 * 64];  // [key][d], chunk-swizzled
  __shared__ __align__(16) _Float16 Vs[2][64 * 64];  // [d][key], chunk-swizzled

  const int tid = threadIdx.x, w = tid >> 6;
  const int l31 = tid & 31, hi = (tid & 63) >> 5;
  const int h = blockIdx.x, b = blockIdx.y, qb = blockIdx.z * 256;
  const float NEGINF = -__builtin_inff();

  const int kr = tid >> 3;
  const int ch = (tid & 7) ^ (kr & 7);
  const _Float16* kSrc = Kg + (size_t)(b * Sk + kr) * Uk + h * 64 + ch * 8;
  const _Float16* vSrc = Vtg + (size_t)((b * Hk + h) * 64 + kr) * Sk + ch * 8;

  g2l16(kSrc, (char*)Ks[0] + w * 1024);
  g2l16(vSrc, (char*)Vs[0] + w * 1024);

  const int qrow = qb + w * 32 + l31;
  const size_t qoff = (size_t)(b * Sk + qrow) * Uk + h * 64 + hi * 8;
  half8 qf[4];
#pragma unroll
  for (int kc = 0; kc < 4; ++kc) qf[kc] = *(const half8*)&Qg[qoff + kc * 16];

  const unsigned long long* mrow = mb + (size_t)(b * Sk + qrow) * 32;

  f32x16 accO[2];
#pragma unroll
  for (int dt = 0; dt < 2; ++dt)
#pragma unroll
    for (int r = 0; r < 16; ++r) accO[dt][r] = 0.f;
  float m = NEGINF, l = 0.f;

  int cur = 0;
  __syncthreads();  // tile 0 staged

  for (int it = 0; it < 32; ++it) {
    if (it + 1 < 32) {  // prefetch next tile into the other buffer (flies under compute)
      g2l16(kSrc + (size_t)(it + 1) * 64 * Uk, (char*)Ks[cur ^ 1] + w * 1024);
      g2l16(vSrc + (it + 1) * 64, (char*)Vs[cur ^ 1] + w * 1024);
    }
    const unsigned long long wm = mrow[it];

    // ---- QK^T (swapped: lane <-> q, keys in regs) ----
    f32x16 sc[2];
#pragma unroll
    for (int n = 0; n < 2; ++n)
#pragma unroll
      for (int r = 0; r < 16; ++r) sc[n][r] = 0.f;
    __builtin_amdgcn_s_setprio(1);
#pragma unroll
    for (int n = 0; n < 2; ++n)
#pragma unroll
      for (int kc = 0; kc < 4; ++kc) {
        half8 kf = *(const half8*)&Ks[cur][(n * 32 + l31) * 64 + ((kc * 2 + hi) ^ (l31 & 7)) * 8];
        sc[n] = __builtin_amdgcn_mfma_f32_32x32x16_f16(kf, qf[kc], sc[n], 0, 0, 0);
      }
    __builtin_amdgcn_s_setprio(0);

    // ---- mask (skipped when tile fully enabled) ----
    const bool tmask = !__all(wm == ~0ULL);
    if (tmask) {
#pragma unroll
      for (int n = 0; n < 2; ++n)
#pragma unroll
        for (int r = 0; r < 16; ++r) {
          int off = n * 32 + (r & 3) + 8 * (r >> 2) + (hi << 2);
          sc[n][r] = ((wm >> off) & 1ULL) ? sc[n][r] : NEGINF;
        }
    }

    // ---- row max: 4 interleaved chains + tree tail (compiler can't reassociate) ----
    float mx0 = NEGINF, mx1 = NEGINF, mx2 = NEGINF, mx3 = NEGINF;
#pragma unroll
    for (int n = 0; n < 2; ++n)
#pragma unroll
      for (int g = 0; g < 4; ++g) {
        mx0 = fmaxf(mx0, sc[n][4 * g + 0]);
        mx1 = fmaxf(mx1, sc[n][4 * g + 1]);
        mx2 = fmaxf(mx2, sc[n][4 * g + 2]);
        mx3 = fmaxf(mx3, sc[n][4 * g + 3]);
      }
    float mx = fmaxf(fmaxf(mx0, mx1), fmaxf(mx2, mx3));
    mx = fmaxf(mx, __shfl_xor(mx, 32));

    const bool skip = __all(mx <= m + 8.f);  // deferred rescale (T13)
    float alpha = 1.f;
    if (!skip) {
      float mn = fmaxf(m, mx);
      alpha = (mn > NEGINF) ? __expf(m - mn) : 0.f;
      m = mn;
    }

    // ---- fused exp + pack: sc dies as pkL/pkH is born (register-pressure fix) ----
    // clamp to -80 unconditionally: dead rows give s=NaN -> fmaxf(NaN,-80)=-80 -> exp~0
    unsigned int pkL[2][4], pkH[2][4];
    float rs0 = 0.f, rs1 = 0.f, rs2 = 0.f, rs3 = 0.f;
#pragma unroll
    for (int n = 0; n < 2; ++n)
#pragma unroll
      for (int g = 0; g < 4; ++g) {
        float e0 = __expf(fmaxf(sc[n][4 * g + 0] - m, -80.f));
        float e1 = __expf(fmaxf(sc[n][4 * g + 1] - m, -80.f));
        float e2 = __expf(fmaxf(sc[n][4 * g + 2] - m, -80.f));
        float e3 = __expf(fmaxf(sc[n][4 * g + 3] - m, -80.f));
        rs0 += e0; rs1 += e1; rs2 += e2; rs3 += e3;
        pkL[n][g] = pkrtz(e0, e1);
        pkH[n][g] = pkrtz(e2, e3);
      }
    float rs = (rs0 + rs1) + (rs2 + rs3);
    rs += __shfl_xor(rs, 32);
    l = l * alpha + rs;
    if (!skip) {  // rare (iter 0 + genuinely-new-max tiles): broadcast alpha per q-reg
#pragma unroll
      for (int r = 0; r < 16; ++r) {
        float ar = __shfl(alpha, (r & 3) + 8 * (r >> 2) + (hi << 2));
        accO[0][r] *= ar;
        accO[1][r] *= ar;
      }
    }

    // ---- PV: assemble A-frags via half-exchange, 2 mfma per kt ----
#pragma unroll
    for (int kt = 0; kt < 4; ++kt) {
      const int n = kt >> 1, t = kt & 1;
      unsigned int s0 = __shfl_xor((int)(hi ? pkL[n][2 * t] : pkL[n][2 * t + 1]), 32);
      unsigned int s1 = __shfl_xor((int)(hi ? pkH[n][2 * t] : pkH[n][2 * t + 1]), 32);
      unsigned int o0 = hi ? pkL[n][2 * t + 1] : pkL[n][2 * t];
      unsigned int o1 = hi ? pkH[n][2 * t + 1] : pkH[n][2 * t];
      union { half8 hh; unsigned int u[4]; } pa;
      pa.u[0] = hi ? s0 : o0;
      pa.u[1] = hi ? s1 : o1;
      pa.u[2] = hi ? o0 : s0;
      pa.u[3] = hi ? o1 : s1;
      __builtin_amdgcn_s_setprio(1);
#pragma unroll
      for (int dt = 0; dt < 2; ++dt) {
        half8 vf = *(const half8*)&Vs[cur][(dt * 32 + l31) * 64 + ((kt * 2 + hi) ^ (l31 & 7)) * 8];
        accO[dt] = __builtin_amdgcn_mfma_f32_32x32x16_f16(pa.hh, vf, accO[dt], 0, 0, 0);
      }
      __builtin_amdgcn_s_setprio(0);
    }
    __syncthreads();  // next tile staged & all reads of cur done
    cur ^= 1;
  }

  // ---- epilogue: /l (per-q via shfl), coalesced fp16 stores ----
  float inv = (l > 1e-30f) ? 1.0f / l : 0.0f;
#pragma unroll
  for (int r = 0; r < 16; ++r) {
    const int qd = (r & 3) + 8 * (r >> 2) + 4 * hi;
    float invr = __shfl(inv, qd);
#pragma unroll
    for (int dt = 0; dt < 2; ++dt)
      Cg[(size_t)(b * Sk + qb + w * 32 + qd) * Uk + h * 64 + dt * 32 + l31] =
          (_Float16)(accO[dt][r] * invr);
  }
}

// ---------- launch ----------
extern "C" void kernel_launch(void* const* d_in, const int* in_sizes, int n_in,
                              void* d_out, int out_size, void* d_ws, size_t ws_size,
                              hipStream_t stream) {
  const float* x = (const float*)d_in[0];
  const unsigned char* mask = (const unsigned char*)d_in[1];
  const float* wq = (const float*)d_in[2];
  const float* wk = (const float*)d_in[3];
  const float* wv = (const float*)d_in[4];
  const float* wo = (const float*)d_in[5];
  float* out = (float*)d_out;

  char* ws = (char*)d_ws;
  _Float16* wt  = (_Float16*)(ws);                       // 8 MB
  _Float16* x16 = (_Float16*)(ws + (8ull << 20));        // 16 MB
  _Float16* c16 = x16;                                   // alias: x16 dead after QKV GEMMs
  _Float16* qkv = (_Float16*)(ws + (24ull << 20));       // 48 MB
  _Float16* vt  = (_Float16*)(ws + (72ull << 20));       // 16 MB
  unsigned long long* mbw = (unsigned long long*)(ws + (88ull << 20));  // 2 MB
  int* mflag = (int*)(ws + (90ull << 20));

  const size_t MU = (size_t)Bk * Sk * Uk;

  sniff_mask_kernel<<<dim3(1), dim3(256), 0, stream>>>(mask, mflag);
  mask_bits_kernel<<<dim3(1024), dim3(256), 0, stream>>>(mask, mflag, mbw, Bk * Sk * (Sk / 64));
  convert_x_kernel<<<dim3(8192), dim3(256), 0, stream>>>(x, x16, (int)(MU / 4));
  convert_wt_kernel<<<dim3(16, 16, 4), dim3(256), 0, stream>>>(wq, wk, wv, wo, wt);
  gemm_qkv_kernel<<<dim3(64, 8, 3), dim3(256), 0, stream>>>(x16, wt, qkv);
  transpose_v_kernel<<<dim3(32, 64), dim3(256), 0, stream>>>(qkv + 2 * MU, vt);
  attn_kernel<<<dim3(Hk, Bk, Sk / 256), dim3(512), 0, stream>>>(qkv, qkv + MU, vt, mbw, c16);
  gemm_out_kernel<<<dim3(64, 8), dim3(256), 0, stream>>>(c16, wt + 3ull * Uk * Uk, out);
}

// Round 6
// 392.787 us; speedup vs baseline: 1.5239x; 1.2730x over previous
//
#include <hip/hip_runtime.h>
#include <hip/hip_fp16.h>

typedef _Float16 half8 __attribute__((ext_vector_type(8)));
typedef _Float16 half4 __attribute__((ext_vector_type(4)));
typedef __fp16 fp16x2 __attribute__((ext_vector_type(2)));
typedef float floatx4 __attribute__((ext_vector_type(4)));
typedef float f32x16 __attribute__((ext_vector_type(16)));

#define DEV __device__ __forceinline__

static constexpr int Bk = 4, Sk = 2048, Uk = 1024, Hk = 16;

DEV void g2l16(const void* g, void* l) {
  __builtin_amdgcn_global_load_lds(
      (const __attribute__((address_space(1))) void*)g,
      (__attribute__((address_space(3))) void*)l, 16, 0, 0);
}

DEV unsigned int pkrtz(float a, float b) {
  union { fp16x2 h; unsigned int u; } t;
  t.h = __builtin_amdgcn_cvt_pkrtz(a, b);
  return t.u;
}

// ---------- mask (int32 bool per harness contract; layout bench-proven r2/r4/r5)
// -> u64 bit words, 1 bit per key ----------
__global__ void mask_bits_kernel(const int* __restrict__ mask,
                                 unsigned long long* __restrict__ mb, int nwords) {
  int t = blockIdx.x * blockDim.x + threadIdx.x;
  if (t >= nwords) return;
  unsigned long long bits = 0ULL;
  const int4* p = (const int4*)mask + (size_t)t * 16;
#pragma unroll
  for (int j = 0; j < 16; ++j) {
    int4 v = p[j];
    bits |= (unsigned long long)(v.x != 0) << (4 * j + 0);
    bits |= (unsigned long long)(v.y != 0) << (4 * j + 1);
    bits |= (unsigned long long)(v.z != 0) << (4 * j + 2);
    bits |= (unsigned long long)(v.w != 0) << (4 * j + 3);
  }
  mb[t] = bits;
}

// ---------- fp32 -> fp16 ----------
__global__ void convert_x_kernel(const float* __restrict__ X, _Float16* __restrict__ O, int n4) {
  int i = blockIdx.x * blockDim.x + threadIdx.x;
  if (i >= n4) return;
  float4 v = ((const float4*)X)[i];
  half4 o = { (_Float16)v.x, (_Float16)v.y, (_Float16)v.z, (_Float16)v.w };
  ((half4*)O)[i] = o;
}

// ---------- weights: fp32 [K][N] -> fp16 transposed [N][K] ----------
__global__ __launch_bounds__(256) void convert_wt_kernel(
    const float* __restrict__ W0, const float* __restrict__ W1,
    const float* __restrict__ W2, const float* __restrict__ W3,
    _Float16* __restrict__ Out) {
  __shared__ _Float16 t[64][66];
  int z = blockIdx.z;
  const float* W = (z == 0) ? W0 : (z == 1) ? W1 : (z == 2) ? W2 : W3;
  _Float16* O = Out + (size_t)z * Uk * Uk;
  int kt = blockIdx.x * 64, nt = blockIdx.y * 64;
  int c = threadIdx.x & 63, r4 = threadIdx.x >> 6;
#pragma unroll
  for (int j = 0; j < 16; ++j) {
    int rr = j * 4 + r4;
    t[rr][c] = (_Float16)W[(size_t)(kt + rr) * Uk + nt + c];
  }
  __syncthreads();
#pragma unroll
  for (int j = 0; j < 16; ++j) {
    int rr = j * 4 + r4;
    O[(size_t)(nt + rr) * Uk + kt + c] = t[c][rr];
  }
}

// ---------- V [B,S,H*64] -> Vt [B,H,64,S] ----------
__global__ __launch_bounds__(256) void transpose_v_kernel(
    const _Float16* __restrict__ V, _Float16* __restrict__ Vt) {
  __shared__ _Float16 t[64][66];
  int st = blockIdx.x * 64;
  int bh = blockIdx.y, b = bh >> 4, h = bh & 15;
  int c = threadIdx.x & 63, r4 = threadIdx.x >> 6;
#pragma unroll
  for (int j = 0; j < 16; ++j) {
    int rr = j * 4 + r4;
    t[rr][c] = V[(size_t)(b * Sk + st + rr) * Uk + h * 64 + c];
  }
  __syncthreads();
#pragma unroll
  for (int j = 0; j < 16; ++j) {
    int rr = j * 4 + r4;
    Vt[(size_t)((b * Hk + h) * 64 + rr) * Sk + st + c] = t[c][rr];
  }
}

// ---------- GEMM body: C[M,N] = A[M,K] @ Bt[N,K]^T, m97-style 128x128/BK=32 ----------
template <typename OUT_T>
DEV void gemm_body(const _Float16* __restrict__ A, const _Float16* __restrict__ Bt,
                   OUT_T* __restrict__ C, int M, int N, int K, float scale) {
  __shared__ __align__(16) _Float16 As[128 * 32];
  __shared__ __align__(16) _Float16 Bs[128 * 32];
  int tid = threadIdx.x, w = tid >> 6, lane = tid & 63;
  int lr = lane & 15, lg = lane >> 4;
  int wm = w >> 1, wn = w & 1;
  int bm = blockIdx.x * 128, bn = blockIdx.y * 128;

  floatx4 acc[4][4];
#pragma unroll
  for (int m = 0; m < 4; ++m)
#pragma unroll
    for (int n = 0; n < 4; ++n) acc[m][n] = (floatx4){0.f, 0.f, 0.f, 0.f};

  for (int k0 = 0; k0 < K; k0 += 32) {
#pragma unroll
    for (int is = 0; is < 2; ++is) {
      int idx = is * 256 + tid;
      g2l16(&A[(size_t)(bm + (idx >> 2)) * K + k0 + (idx & 3) * 8],
            (char*)As + (is * 256 + w * 64) * 16);
    }
#pragma unroll
    for (int is = 0; is < 2; ++is) {
      int idx = is * 256 + tid;
      g2l16(&Bt[(size_t)(bn + (idx >> 2)) * K + k0 + (idx & 3) * 8],
            (char*)Bs + (is * 256 + w * 64) * 16);
    }
    __syncthreads();

    half8 af[4], bf[4];
#pragma unroll
    for (int m = 0; m < 4; ++m) af[m] = *(const half8*)&As[(wm * 64 + m * 16 + lr) * 32 + lg * 8];
#pragma unroll
    for (int n = 0; n < 4; ++n) bf[n] = *(const half8*)&Bs[(wn * 64 + n * 16 + lr) * 32 + lg * 8];
#pragma unroll
    for (int m = 0; m < 4; ++m)
#pragma unroll
      for (int n = 0; n < 4; ++n)
        acc[m][n] = __builtin_amdgcn_mfma_f32_16x16x32_f16(af[m], bf[n], acc[m][n], 0, 0, 0);
    __syncthreads();
  }

#pragma unroll
  for (int m = 0; m < 4; ++m)
#pragma unroll
    for (int n = 0; n < 4; ++n)
#pragma unroll
      for (int r = 0; r < 4; ++r) {
        int row = bm + wm * 64 + m * 16 + lg * 4 + r;
        int col = bn + wn * 64 + n * 16 + lr;
        C[(size_t)row * N + col] = (OUT_T)(acc[m][n][r] * scale);
      }
}

__global__ __launch_bounds__(256) void gemm_qkv_kernel(
    const _Float16* __restrict__ A, const _Float16* __restrict__ WtBase,
    _Float16* __restrict__ OutBase) {
  int z = blockIdx.z;
  const _Float16* Bt = WtBase + (size_t)z * Uk * Uk;
  _Float16* Co = OutBase + (size_t)z * (Bk * Sk) * Uk;
  float scale = (z == 0) ? 0.125f : 1.0f;
  gemm_body<_Float16>(A, Bt, Co, Bk * Sk, Uk, Uk, scale);
}

__global__ __launch_bounds__(256) void gemm_out_kernel(
    const _Float16* __restrict__ A, const _Float16* __restrict__ Bt,
    float* __restrict__ C) {
  gemm_body<float>(A, Bt, C, Bk * Sk, Uk, Uk, 1.0f);
}

// ---------- flash attention, 4-wave blocks, 32x32 swapped-QK^T in-register softmax ----
// 256-thread blocks: wave/SIMD granularity is 1 (512-thread blocks quantize to {2,4}).
// __launch_bounds__(256,3) => reg budget ~170/wave; live set ~140 => no spill at
// 3 waves/SIMD (round-5: 512-thread/(512,4) capped at 128 regs -> 75MB scratch writes).
__global__ __launch_bounds__(256, 3) void attn_kernel(
    const _Float16* __restrict__ Qg,   // [B*S, U], pre-scaled by 1/8
    const _Float16* __restrict__ Kg,   // [B*S, U]
    const _Float16* __restrict__ Vtg,  // [B*H*64, S]
    const unsigned long long* __restrict__ mb,  // [B*S, 32] bit words
    _Float16* __restrict__ Cg) {       // [B*S, U]
  __shared__ __align__(16) _Float16 Ks[2][64 * 64];  // [key][d], chunk-swizzled
  __shared__ __align__(16) _Float16 Vs[2][64 * 64];  // [d][key], chunk-swizzled

  const int tid = threadIdx.x, w = tid >> 6;         // w in 0..3
  const int l31 = tid & 31, hi = (tid & 63) >> 5;
  const int h = blockIdx.x, b = blockIdx.y, qb = blockIdx.z * 128;
  const float NEGINF = -__builtin_inff();

  // staging: thread covers rows kr and kr+32; source chunk pre-swizzled (G4 both-sides)
  const int kr = tid >> 3;                            // 0..31
  const int ch = (tid & 7) ^ (kr & 7);                // (kr+32)&7 == kr&7
  const _Float16* kSrcA = Kg + (size_t)(b * Sk + kr) * Uk + h * 64 + ch * 8;
  const _Float16* kSrcB = kSrcA + (size_t)32 * Uk;
  const _Float16* vSrcA = Vtg + (size_t)((b * Hk + h) * 64 + kr) * Sk + ch * 8;
  const _Float16* vSrcB = vSrcA + (size_t)32 * Sk;

  // stage tile 0 into buffer 0 (LDS dest: linear, wave covers 1KB per call)
  g2l16(kSrcA, (char*)Ks[0] + w * 1024);
  g2l16(kSrcB, (char*)Ks[0] + 4096 + w * 1024);
  g2l16(vSrcA, (char*)Vs[0] + w * 1024);
  g2l16(vSrcB, (char*)Vs[0] + 4096 + w * 1024);

  const int qrow = qb + w * 32 + l31;
  const size_t qoff = (size_t)(b * Sk + qrow) * Uk + h * 64 + hi * 8;
  half8 qf[4];
#pragma unroll
  for (int kc = 0; kc < 4; ++kc) qf[kc] = *(const half8*)&Qg[qoff + kc * 16];

  const unsigned long long* mrow = mb + (size_t)(b * Sk + qrow) * 32;

  f32x16 accO[2];
#pragma unroll
  for (int dt = 0; dt < 2; ++dt)
#pragma unroll
    for (int r = 0; r < 16; ++r) accO[dt][r] = 0.f;
  float m = NEGINF, l = 0.f;

  int cur = 0;
  __syncthreads();  // tile 0 staged

  for (int it = 0; it < 32; ++it) {
    if (it + 1 < 32) {  // prefetch next tile into the other buffer (flies under compute)
      char* kd = (char*)Ks[cur ^ 1] + w * 1024;
      char* vd = (char*)Vs[cur ^ 1] + w * 1024;
      g2l16(kSrcA + (size_t)(it + 1) * 64 * Uk, kd);
      g2l16(kSrcB + (size_t)(it + 1) * 64 * Uk, kd + 4096);
      g2l16(vSrcA + (it + 1) * 64, vd);
      g2l16(vSrcB + (it + 1) * 64, vd + 4096);
    }
    const unsigned long long wm = mrow[it];

    // ---- QK^T (swapped: lane <-> q, keys in regs) ----
    f32x16 sc[2];
#pragma unroll
    for (int n = 0; n < 2; ++n)
#pragma unroll
      for (int r = 0; r < 16; ++r) sc[n][r] = 0.f;
    __builtin_amdgcn_s_setprio(1);
#pragma unroll
    for (int n = 0; n < 2; ++n)
#pragma unroll
      for (int kc = 0; kc < 4; ++kc) {
        half8 kf = *(const half8*)&Ks[cur][(n * 32 + l31) * 64 + ((kc * 2 + hi) ^ (l31 & 7)) * 8];
        sc[n] = __builtin_amdgcn_mfma_f32_32x32x16_f16(kf, qf[kc], sc[n], 0, 0, 0);
      }
    __builtin_amdgcn_s_setprio(0);

    // ---- mask (skipped when tile fully enabled) ----
    const bool tmask = !__all(wm == ~0ULL);
    if (tmask) {
#pragma unroll
      for (int n = 0; n < 2; ++n)
#pragma unroll
        for (int r = 0; r < 16; ++r) {
          int off = n * 32 + (r & 3) + 8 * (r >> 2) + (hi << 2);
          sc[n][r] = ((wm >> off) & 1ULL) ? sc[n][r] : NEGINF;
        }
    }

    // ---- row max: 4 interleaved chains + tree tail ----
    float mx0 = NEGINF, mx1 = NEGINF, mx2 = NEGINF, mx3 = NEGINF;
#pragma unroll
    for (int n = 0; n < 2; ++n)
#pragma unroll
      for (int g = 0; g < 4; ++g) {
        mx0 = fmaxf(mx0, sc[n][4 * g + 0]);
        mx1 = fmaxf(mx1, sc[n][4 * g + 1]);
        mx2 = fmaxf(mx2, sc[n][4 * g + 2]);
        mx3 = fmaxf(mx3, sc[n][4 * g + 3]);
      }
    float mx = fmaxf(fmaxf(mx0, mx1), fmaxf(mx2, mx3));
    mx = fmaxf(mx, __shfl_xor(mx, 32));

    const bool skip = __all(mx <= m + 8.f);  // deferred rescale (T13)
    float alpha = 1.f;
    if (!skip) {
      float mn = fmaxf(m, mx);
      alpha = (mn > NEGINF) ? __expf(m - mn) : 0.f;
      m = mn;
    }

    // ---- fused exp + pack: sc dies as pkL/pkH is born ----
    // clamp -80 unconditionally: dead rows s=NaN -> fmaxf(NaN,-80)=-80 -> exp~0
    unsigned int pkL[2][4], pkH[2][4];
    float rs0 = 0.f, rs1 = 0.f, rs2 = 0.f, rs3 = 0.f;
#pragma unroll
    for (int n = 0; n < 2; ++n)
#pragma unroll
      for (int g = 0; g < 4; ++g) {
        float e0 = __expf(fmaxf(sc[n][4 * g + 0] - m, -80.f));
        float e1 = __expf(fmaxf(sc[n][4 * g + 1] - m, -80.f));
        float e2 = __expf(fmaxf(sc[n][4 * g + 2] - m, -80.f));
        float e3 = __expf(fmaxf(sc[n][4 * g + 3] - m, -80.f));
        rs0 += e0; rs1 += e1; rs2 += e2; rs3 += e3;
        pkL[n][g] = pkrtz(e0, e1);
        pkH[n][g] = pkrtz(e2, e3);
      }
    float rs = (rs0 + rs1) + (rs2 + rs3);
    rs += __shfl_xor(rs, 32);
    l = l * alpha + rs;
    if (!skip) {  // rare: broadcast alpha per accO q-reg
#pragma unroll
      for (int r = 0; r < 16; ++r) {
        float ar = __shfl(alpha, (r & 3) + 8 * (r >> 2) + (hi << 2));
        accO[0][r] *= ar;
        accO[1][r] *= ar;
      }
    }

    // ---- PV: assemble A-frags via half-exchange, 2 mfma per kt ----
#pragma unroll
    for (int kt = 0; kt < 4; ++kt) {
      const int n = kt >> 1, t = kt & 1;
      unsigned int s0 = __shfl_xor((int)(hi ? pkL[n][2 * t] : pkL[n][2 * t + 1]), 32);
      unsigned int s1 = __shfl_xor((int)(hi ? pkH[n][2 * t] : pkH[n][2 * t + 1]), 32);
      unsigned int o0 = hi ? pkL[n][2 * t + 1] : pkL[n][2 * t];
      unsigned int o1 = hi ? pkH[n][2 * t + 1] : pkH[n][2 * t];
      union { half8 hh; unsigned int u[4]; } pa;
      pa.u[0] = hi ? s0 : o0;
      pa.u[1] = hi ? s1 : o1;
      pa.u[2] = hi ? o0 : s0;
      pa.u[3] = hi ? o1 : s1;
      __builtin_amdgcn_s_setprio(1);
#pragma unroll
      for (int dt = 0; dt < 2; ++dt) {
        half8 vf = *(const half8*)&Vs[cur][(dt * 32 + l31) * 64 + ((kt * 2 + hi) ^ (l31 & 7)) * 8];
        accO[dt] = __builtin_amdgcn_mfma_f32_32x32x16_f16(pa.hh, vf, accO[dt], 0, 0, 0);
      }
      __builtin_amdgcn_s_setprio(0);
    }
    __syncthreads();  // next tile staged & all reads of cur done
    cur ^= 1;
  }

  // ---- epilogue: /l (per-q via shfl), coalesced fp16 stores ----
  float inv = (l > 1e-30f) ? 1.0f / l : 0.0f;
#pragma unroll
  for (int r = 0; r < 16; ++r) {
    const int qd = (r & 3) + 8 * (r >> 2) + 4 * hi;
    float invr = __shfl(inv, qd);
#pragma unroll
    for (int dt = 0; dt < 2; ++dt)
      Cg[(size_t)(b * Sk + qb + w * 32 + qd) * Uk + h * 64 + dt * 32 + l31] =
          (_Float16)(accO[dt][r] * invr);
  }
}

// ---------- launch ----------
extern "C" void kernel_launch(void* const* d_in, const int* in_sizes, int n_in,
                              void* d_out, int out_size, void* d_ws, size_t ws_size,
                              hipStream_t stream) {
  const float* x = (const float*)d_in[0];
  const int* mask = (const int*)d_in[1];
  const float* wq = (const float*)d_in[2];
  const float* wk = (const float*)d_in[3];
  const float* wv = (const float*)d_in[4];
  const float* wo = (const float*)d_in[5];
  float* out = (float*)d_out;

  char* ws = (char*)d_ws;
  _Float16* wt  = (_Float16*)(ws);                       // 8 MB
  _Float16* x16 = (_Float16*)(ws + (8ull << 20));        // 16 MB
  _Float16* c16 = x16;                                   // alias: x16 dead after QKV GEMMs
  _Float16* qkv = (_Float16*)(ws + (24ull << 20));       // 48 MB
  _Float16* vt  = (_Float16*)(ws + (72ull << 20));       // 16 MB
  unsigned long long* mbw = (unsigned long long*)(ws + (88ull << 20));  // 2 MB

  const size_t MU = (size_t)Bk * Sk * Uk;

  mask_bits_kernel<<<dim3(1024), dim3(256), 0, stream>>>(mask, mbw, Bk * Sk * (Sk / 64));
  convert_x_kernel<<<dim3(8192), dim3(256), 0, stream>>>(x, x16, (int)(MU / 4));
  convert_wt_kernel<<<dim3(16, 16, 4), dim3(256), 0, stream>>>(wq, wk, wv, wo, wt);
  gemm_qkv_kernel<<<dim3(64, 8, 3), dim3(256), 0, stream>>>(x16, wt, qkv);
  transpose_v_kernel<<<dim3(32, 64), dim3(256), 0, stream>>>(qkv + 2 * MU, vt);
  attn_kernel<<<dim3(Hk, Bk, Sk / 128), dim3(256), 0, stream>>>(qkv, qkv + MU, vt, mbw, c16);
  gemm_out_kernel<<<dim3(64, 8), dim3(256), 0, stream>>>(c16, wt + 3ull * Uk * Uk, out);
}